// Round 12
// baseline (582.145 us; speedup 1.0000x reference)
//
#include <hip/hip_runtime.h>
#include <stdint.h>

typedef float    f32x4  __attribute__((ext_vector_type(4)));
typedef float    f32x16 __attribute__((ext_vector_type(16)));
typedef int      i32x4  __attribute__((ext_vector_type(4)));
typedef int      i32x8  __attribute__((ext_vector_type(8)));
typedef uint32_t u32x4  __attribute__((ext_vector_type(4)));

constexpr int Mdim = 8192;    // B*S = 4*2048
constexpr int Ndim = 14336;
constexpr int Kdim = 4096;
constexpr int BM = 256, BN = 256, BK = 128;
constexpr int NT = Kdim / BK;        // 32 K-tiles
constexpr int NWFLAT = (Ndim / 32) * 4;   // 1792 w-flat blocks

#define VMCNT(n) do { asm volatile("s_waitcnt vmcnt(" #n ")" ::: "memory"); \
                      __builtin_amdgcn_sched_barrier(0); } while (0)
#define LGKM(n)  do { asm volatile("s_waitcnt lgkmcnt(" #n ")" ::: "memory"); \
                      __builtin_amdgcn_sched_barrier(0); } while (0)
#define BARRIER() do { asm volatile("" ::: "memory"); \
                       __builtin_amdgcn_s_barrier(); \
                       asm volatile("" ::: "memory"); } while (0)

__device__ __forceinline__ void gload_lds16(const void* g, void* l) {
  __builtin_amdgcn_global_load_lds(
      (const __attribute__((address_space(1))) unsigned int*)g,
      (__attribute__((address_space(3))) unsigned int*)l, 16, 0, 0);
}

__device__ __forceinline__ i32x4 ldsr128(const uint8_t* p) {
  i32x4 r;
  asm volatile("ds_read_b128 %0, %1"
               : "=v"(r)
               : "v"((const __attribute__((address_space(3))) uint8_t*)p));
  return r;
}

// A-fragment read: 32 contiguous logical bytes at logical byte kb of row
// `row`; physical byte = logical ^ ((row&7)<<4)  (T2 swizzle, rule #21).
__device__ __forceinline__ i32x8 frag(const uint8_t* tile, int row, int kb) {
  const int p0 = kb ^ ((row & 7) << 4);
  const uint8_t* rp = tile + row * BK;
  i32x4 lo = ldsr128(rp + p0);
  i32x4 hi = ldsr128(rp + (p0 ^ 16));
  return __builtin_shufflevector(lo, hi, 0, 1, 2, 3, 4, 5, 6, 7);
}

__device__ __forceinline__ f32x16 mx(i32x8 a, i32x8 b, f32x16 c) {
  // unit e8m0 scales (0x7f = 2^0): bit-identical to plain fp8 matmul, 2x rate
  return __builtin_amdgcn_mfma_scale_f32_32x32x64_f8f6f4(
      a, b, c, 0, 0, 0, 0x7f7f7f7f, 0, 0x7f7f7f7f);
}

// Merged prepass, one launch:
//  blocks [0, NWFLAT): weight quant + reorder into MFMA-native flat layout
//    B'[(n0*64+k0)*2048 + l*32 + j] = fp8(w[n0*32+(l&31)][k0*64+(l>>5)*32+j])
//    (exact: w values are e4m3 lattice points), via LDS (padded [32][260]).
//  blocks [NWFLAT, ...): x quant, q = e4m3(clip(x/iscale, +-448)), RNE via
//    v_cvt_pk_fp8_f32, grid-stride, 8 elems/thread.
__global__ void __launch_bounds__(256) prepass_kernel(
    const float* __restrict__ x, const float* __restrict__ w,
    uint8_t* __restrict__ qx, uint8_t* __restrict__ qwf,
    const float* __restrict__ iscale, long long nx, int nblk_x)
{
  __shared__ uint32_t lds[32][260];
  const int bid = blockIdx.x;
  const int tid = threadIdx.x;
  if (bid < NWFLAT) {
    const int n0 = bid >> 2;         // 0..447
    const int kq = bid & 3;          // 0..3 (1024-k quarters)
#pragma unroll 4
    for (int r = 0; r < 32; ++r) {
      const float* src =
          w + (long long)(n0 * 32 + r) * Kdim + kq * 1024 + tid * 4;
      f32x4 v = *(const f32x4*)src;
      float q0 = fminf(fmaxf(v[0], -448.f), 448.f);
      float q1 = fminf(fmaxf(v[1], -448.f), 448.f);
      float q2 = fminf(fmaxf(v[2], -448.f), 448.f);
      float q3 = fminf(fmaxf(v[3], -448.f), 448.f);
      unsigned int pk = 0;
      pk = __builtin_amdgcn_cvt_pk_fp8_f32(q0, q1, pk, false);
      pk = __builtin_amdgcn_cvt_pk_fp8_f32(q2, q3, pk, true);
      lds[r][tid] = pk;
    }
    __syncthreads();
#pragma unroll
    for (int i = 0; i < 4; ++i) {
      const int it  = i * 256 + tid;
      const int k0l = it >> 6;        // 0..15
      const int l   = it & 63;
      const uint32_t* src = &lds[l & 31][k0l * 16 + (l >> 5) * 8];
      u32x4 lo = *(const u32x4*)src;
      u32x4 hi = *(const u32x4*)(src + 4);
      uint8_t* dst =
          qwf + (long long)(n0 * 64 + kq * 16 + k0l) * 2048 + l * 32;
      *(u32x4*)dst = lo;
      *(u32x4*)(dst + 16) = hi;
    }
  } else {
    const float sx = iscale[0];
    const long long ncx = nx >> 3;
    const long long idx = (long long)(bid - NWFLAT) * 256 + tid;
    const long long stride = (long long)nblk_x * 256;
    for (long long c = idx; c < ncx; c += stride) {
      f32x4 v0 = *(const f32x4*)(x + c * 8);
      f32x4 v1 = *(const f32x4*)(x + c * 8 + 4);
      float q[8];
#pragma unroll
      for (int j = 0; j < 4; ++j) {
        q[j]     = fminf(fmaxf(v0[j] / sx, -448.f), 448.f);
        q[4 + j] = fminf(fmaxf(v1[j] / sx, -448.f), 448.f);
      }
      unsigned int w0 = 0, w1 = 0;
      w0 = __builtin_amdgcn_cvt_pk_fp8_f32(q[0], q[1], w0, false);
      w0 = __builtin_amdgcn_cvt_pk_fp8_f32(q[2], q[3], w0, true);
      w1 = __builtin_amdgcn_cvt_pk_fp8_f32(q[4], q[5], w1, false);
      w1 = __builtin_amdgcn_cvt_pk_fp8_f32(q[6], q[7], w1, true);
      uint2 r; r.x = w0; r.y = w1;
      *(uint2*)(qx + c * 8) = r;
    }
  }
}

// C = (A @ B^T) * alpha + bias, MX-fp8 unit-scale MFMA.
// 256x256 tile, BK=128, 8 waves (2M x 4N), per-wave 128x64 = 4x2 frags.
// B-DIRECT single-buffered: tile t's 4 B frags are PLAIN C++ i32x8 loads
// from the flat B' layout, issued BEFORE the head VMCNT(4)+barrier so their
// L2/L3 latency hides under the barrier + A ds_read issue.  Compiler's
// post-RA waitcnt pass protects all B uses and RA copies (no R9 hazard);
// only 32 B-regs live (vs R10's 64 -> spill).  A is LDS-staged (2 x 32 KiB,
// T2-swizzled, gload_lds w=16) with R8's proven counted-lgkm pipeline.
// vmcnt audit: at head, outstanding = A-stages(t)[4, issued last tile] then
// B(t)[4]; VMCNT(4) = A-stages retired, B in flight; compiler auto-inserts
// vmcnt(4) before the first B-MFMA (4 newer A-stages outstanding).
// DS demand/tile: 192 -> 128 b128 + half the DMA writes; B rides the TA/L2
// port in parallel with LDS.  2 barriers/tile; setprio (T5); NT stores.
__global__ void __launch_bounds__(512, 2) gemm_fp8_kernel(
    const uint8_t* __restrict__ qa, const uint8_t* __restrict__ qb,
    const float* __restrict__ iscale, const float* __restrict__ wscale,
    const float* __restrict__ bias, float* __restrict__ out)
{
  __shared__ uint8_t smem[2 * 32768];   // 64 KiB: A double-buffer only

  const int tid  = threadIdx.x;
  const int wave = tid >> 6;
  const int lane = tid & 63;
  const int wm   = wave >> 2;       // 0..1
  const int wn   = wave & 3;        // 0..3
  const int col  = lane & 31;
  const int kh   = lane >> 5;
  const long long tile_m = (long long)blockIdx.y * BM;
  const long long tile_n = (long long)blockIdx.x * BN;

  // A staging: unit = 64 rows x 128 B = 8 KiB = 512 thr x 16 B.
  // Thread -> row tid>>3, physical block tid&7; source block = pb ^ (row&7).
  const int urow = tid >> 3;                   // 0..63
  const int pbs  = tid & 7;
  const int scol = (pbs ^ (urow & 7)) << 4;
  const uint8_t* gA = qa + (tile_m + urow) * Kdim + scol;
  uint8_t* lbase = smem + wave * 1024;         // wave-uniform; + lane*16 by HW

#define STAGE(u, k0, boff)                                                \
  gload_lds16(gA + (long long)(u) * 64 * Kdim + (k0),                     \
              lbase + (boff) + (u) * 8192)

  // B' base pointers for this wave's two n0-blocks (frag n=0,1)
  const int n0g0 = (int)(tile_n >> 5) + wn * 2;
  const uint8_t* pB0 = qb + (long long)n0g0 * 131072 + lane * 32;
  const uint8_t* pB1 = pB0 + 131072;

  f32x16 acc[4][2] = {};
  const int rowA = wm * 128 + col;   // + m*32
  const int kb0 = kh * 32;
  const int kb1 = 64 + kh * 32;

  // prologue: stage A(0)
  STAGE(0, 0, 0); STAGE(1, 0, 0); STAGE(2, 0, 0); STAGE(3, 0, 0);

  for (int t = 0; t < NT; ++t) {
    const uint8_t* Ab = smem + ((t & 1) ? 32768u : 0u);
    const int uo = t * 4096;

    // B frags for THIS tile: plain loads, issued before the barrier so
    // latency hides under it (L2/L3-hot after the first block-row).
    i32x8 B00 = *(const i32x8*)(pB0 + uo);
    i32x8 B10 = *(const i32x8*)(pB1 + uo);
    i32x8 B01 = *(const i32x8*)(pB0 + uo + 2048);
    i32x8 B11 = *(const i32x8*)(pB1 + uo + 2048);

    VMCNT(4);    // A(t) stages (issued last tile) retired; B(t) in flight
    BARRIER();   // A(t) visible to all waves

    if (t + 1 < NT) {
      const uint32_t bo = ((t + 1) & 1) ? 32768u : 0u;
      const long long kn = (long long)(t + 1) * BK;
      STAGE(0, kn, bo); STAGE(1, kn, bo); STAGE(2, kn, bo); STAGE(3, kn, bo);
    }

    // A pipeline (R8's proven counted-lgkm ladder, <=6 live frags)
    i32x8 A0 = frag(Ab, rowA +  0, kb0);
    i32x8 A1 = frag(Ab, rowA + 32, kb0);
    i32x8 A2 = frag(Ab, rowA + 64, kb0);
    i32x8 A3 = frag(Ab, rowA + 96, kb0);
    LGKM(4);     // A0,A1 ready; A2,A3 in flight
    __builtin_amdgcn_s_setprio(1);
    acc[0][0] = mx(A0, B00, acc[0][0]);  acc[0][1] = mx(A0, B10, acc[0][1]);
    acc[1][0] = mx(A1, B00, acc[1][0]);  acc[1][1] = mx(A1, B10, acc[1][1]);
    __builtin_amdgcn_s_setprio(0);
    i32x8 A4 = frag(Ab, rowA +  0, kb1);
    i32x8 A5 = frag(Ab, rowA + 32, kb1);
    LGKM(4);     // A2,A3 ready
    __builtin_amdgcn_s_setprio(1);
    acc[2][0] = mx(A2, B00, acc[2][0]);  acc[2][1] = mx(A2, B10, acc[2][1]);
    acc[3][0] = mx(A3, B00, acc[3][0]);  acc[3][1] = mx(A3, B10, acc[3][1]);
    __builtin_amdgcn_s_setprio(0);
    i32x8 A6 = frag(Ab, rowA + 64, kb1);
    i32x8 A7 = frag(Ab, rowA + 96, kb1);
    LGKM(4);     // A4,A5 ready
    __builtin_amdgcn_s_setprio(1);
    acc[0][0] = mx(A4, B01, acc[0][0]);  acc[0][1] = mx(A4, B11, acc[0][1]);
    acc[1][0] = mx(A5, B01, acc[1][0]);  acc[1][1] = mx(A5, B11, acc[1][1]);
    __builtin_amdgcn_s_setprio(0);
    LGKM(0);     // A6,A7 ready; ALL my reads of Ab done
    BARRIER();   // every wave past lgkm(0): A(t) fully read; t+1 may
                 // overwrite the other buffer safely next iteration
    __builtin_amdgcn_s_setprio(1);
    acc[2][0] = mx(A6, B01, acc[2][0]);  acc[2][1] = mx(A6, B11, acc[2][1]);
    acc[3][0] = mx(A7, B01, acc[3][0]);  acc[3][1] = mx(A7, B11, acc[3][1]);
    __builtin_amdgcn_s_setprio(0);
  }

  // Epilogue.  C/D layout (32x32, dtype-independent): col = lane&31,
  // row = (r&3) + 8*(r>>2) + 4*kh, r in [0,16).  Non-temporal stores keep
  // the streaming output from evicting A/B' out of L3 (R11 win).
  const float alpha = iscale[0] * wscale[0];
  const long long col0 = tile_n + wn * 64 + col;
  const float bv0 = bias[col0];
  const float bv1 = bias[col0 + 32];
#pragma unroll
  for (int m = 0; m < 4; ++m) {
#pragma unroll
    for (int r = 0; r < 16; ++r) {
      const long long row =
          tile_m + wm * 128 + m * 32 + (r & 3) + 8 * (r >> 2) + 4 * kh;
      float* op = out + row * (long long)Ndim + col0;
      __builtin_nontemporal_store(acc[m][0][r] * alpha + bv0, op);
      __builtin_nontemporal_store(acc[m][1][r] * alpha + bv1, op + 32);
    }
  }
#undef STAGE
}

extern "C" void kernel_launch(void* const* d_in, const int* in_sizes, int n_in,
                              void* d_out, int out_size, void* d_ws, size_t ws_size,
                              hipStream_t stream) {
  const float* x      = (const float*)d_in[0];  // [4,2048,4096]
  const float* weight = (const float*)d_in[1];  // [14336,4096] (e4m3 lattice)
  const float* wscale = (const float*)d_in[2];  // [1]
  const float* iscale = (const float*)d_in[3];  // [1]
  const float* bias   = (const float*)d_in[4];  // [14336]
  float* out = (float*)d_out;                   // [4,2048,14336]

  uint8_t* qx  = (uint8_t*)d_ws;                         // 32 MiB (row-major)
  uint8_t* qwf = qx + (long long)Mdim * Kdim;            // 56 MiB (flat B')

  const long long nx = (long long)Mdim * Kdim;
  const int nblk_x = 2304;

  prepass_kernel<<<NWFLAT + nblk_x, 256, 0, stream>>>(
      x, weight, qx, qwf, iscale, nx, nblk_x);

  dim3 grid(Ndim / BN, Mdim / BM);   // 56 x 32
  gemm_fp8_kernel<<<grid, 512, 0, stream>>>(qx, qwf, iscale, wscale, bias, out);
}

// Round 13
// 560.721 us; speedup vs baseline: 1.0382x; 1.0382x over previous
//
#include <hip/hip_runtime.h>
#include <stdint.h>

typedef float    f32x4  __attribute__((ext_vector_type(4)));
typedef float    f32x16 __attribute__((ext_vector_type(16)));
typedef int      i32x4  __attribute__((ext_vector_type(4)));
typedef int      i32x8  __attribute__((ext_vector_type(8)));
typedef uint32_t u32x4  __attribute__((ext_vector_type(4)));

constexpr int Mdim = 8192;    // B*S = 4*2048
constexpr int Ndim = 14336;
constexpr int Kdim = 4096;
constexpr int BM = 256, BN = 256, BK = 64;
constexpr int NT = Kdim / BK;          // 64 K-steps
constexpr uint32_t SLOT = 32768;       // ring slot: A(16K) + B(16K)

#define VMCNT(n) do { asm volatile("s_waitcnt vmcnt(" #n ")" ::: "memory"); \
                      __builtin_amdgcn_sched_barrier(0); } while (0)
#define LGKM(n)  do { asm volatile("s_waitcnt lgkmcnt(" #n ")" ::: "memory"); \
                      __builtin_amdgcn_sched_barrier(0); } while (0)
#define BARRIER() do { asm volatile("" ::: "memory"); \
                       __builtin_amdgcn_s_barrier(); \
                       asm volatile("" ::: "memory"); } while (0)

__device__ __forceinline__ void gload_lds16(const void* g, void* l) {
  __builtin_amdgcn_global_load_lds(
      (const __attribute__((address_space(1))) unsigned int*)g,
      (__attribute__((address_space(3))) unsigned int*)l, 16, 0, 0);
}

__device__ __forceinline__ i32x4 ldsr128(const uint8_t* p) {
  i32x4 r;
  asm volatile("ds_read_b128 %0, %1"
               : "=v"(r)
               : "v"((const __attribute__((address_space(3))) uint8_t*)p));
  return r;
}

__device__ __forceinline__ f32x16 mx(i32x8 a, i32x8 b, f32x16 c) {
  // unit e8m0 scales (0x7f = 2^0): bit-identical to plain fp8 matmul, 2x rate
  return __builtin_amdgcn_mfma_scale_f32_32x32x64_f8f6f4(
      a, b, c, 0, 0, 0, 0x7f7f7f7f, 0, 0x7f7f7f7f);
}

// Merged prepass (R11): x quant grid-stride + weight quant (w is already on
// the e4m3 lattice -> conversion exact).  q = e4m3(clip(v/s, +-448)), RNE
// via v_cvt_pk_fp8_f32.  One launch saturates HBM.
__global__ void __launch_bounds__(256) quant_both_kernel(
    const float* __restrict__ x, const float* __restrict__ w,
    uint8_t* __restrict__ qx, uint8_t* __restrict__ qw,
    const float* __restrict__ iscale, long long nx, long long nw)
{
  const float sx = iscale[0];
  const long long ncx = nx >> 3, ncw = nw >> 3;
  const long long total = ncx + ncw;
  const long long idx = (long long)blockIdx.x * blockDim.x + threadIdx.x;
  const long long stride = (long long)gridDim.x * blockDim.x;
  for (long long c = idx; c < total; c += stride) {
    const float* in;
    uint8_t* out8;
    float s;
    long long cc;
    if (c < ncx) { in = x; out8 = qx; s = sx;   cc = c; }
    else         { in = w; out8 = qw; s = 1.0f; cc = c - ncx; }
    f32x4 v0 = *(const f32x4*)(in + cc * 8);
    f32x4 v1 = *(const f32x4*)(in + cc * 8 + 4);
    float q[8];
#pragma unroll
    for (int j = 0; j < 4; ++j) {
      q[j]     = fminf(fmaxf(v0[j] / s, -448.f), 448.f);
      q[4 + j] = fminf(fmaxf(v1[j] / s, -448.f), 448.f);
    }
    unsigned int w0 = 0, w1 = 0;
    w0 = __builtin_amdgcn_cvt_pk_fp8_f32(q[0], q[1], w0, false);
    w0 = __builtin_amdgcn_cvt_pk_fp8_f32(q[2], q[3], w0, true);
    w1 = __builtin_amdgcn_cvt_pk_fp8_f32(q[4], q[5], w1, false);
    w1 = __builtin_amdgcn_cvt_pk_fp8_f32(q[6], q[7], w1, true);
    uint2 r; r.x = w0; r.y = w1;
    *(uint2*)(out8 + cc * 8) = r;
  }
}

// C = (A @ B^T) * alpha + bias, MX-fp8 unit-scale MFMA.
// 256x256 tile, BK=64 K-steps, 8 waves (2M x 4N), per-wave 128x64 = 4x2
// frags of 32x32x64.  SYNTHESIS of the two separately-tested mechanisms:
//  (a) DEEP counted-vmcnt staging (R6): 4-slot LDS ring (128 KiB), K-step t
//      computes slot[t&3] while staging t+3 -> 8 loads in flight across
//      every barrier (VMCNT(8) head), prefetch lead ~2.5 K-steps (~2800 cyc)
//      >> 900-cyc HBM latency;
//  (b) dual-barrier PHASE-LOCK (R7/m201): each K-step = 2 phases, each
//      {ds_read subtile + stage half-slot -> barrier -> lgkm(0) ->
//       setprio(1) 4xMFMA setprio(0)}; barrier density (2 per ~1100 cyc)
//      matches the measured-best m201 template.  m218: counted vmcnt only
//      pays INSIDE the phase-locked structure -- the untested combination.
// Ring safety: slot[t] is overwritten while staging t+4 (issued during
// t+1 P0, after t+1's head barrier); every wave passed its P1 LGKM(0)
// (all slot[t] reads done) before that barrier.
//
// T2 swizzle (64-B rows): physical 16B-block = logical ^ ((row>>1)&3);
// pre-swizzled GLOBAL source + linear gload_lds dest + XOR on read (#21).
__global__ void __launch_bounds__(512, 2) gemm_fp8_kernel(
    const uint8_t* __restrict__ qa, const uint8_t* __restrict__ qb,
    const float* __restrict__ iscale, const float* __restrict__ wscale,
    const float* __restrict__ bias, float* __restrict__ out)
{
  __shared__ uint8_t smem[4 * SLOT];   // 128 KiB

  const int tid  = threadIdx.x;
  const int wave = tid >> 6;
  const int lane = tid & 63;
  const int wm   = wave >> 2;       // 0..1
  const int wn   = wave & 3;        // 0..3
  const int col  = lane & 31;
  const int kh   = lane >> 5;
  const long long tile_m = (long long)blockIdx.y * BM;
  const long long tile_n = (long long)blockIdx.x * BN;

  // Staging (R6, verified): unit = 128 rows x 64 B = 8 KiB = 512 thr x 16 B.
  // Thread -> row tid>>2 (0..127), physical block tid&3;
  // global source block = pb ^ ((row>>1)&3).
  const int urow = tid >> 2;
  const int pbs  = tid & 3;
  const int scol = (pbs ^ ((urow >> 1) & 3)) << 4;
  const uint8_t* gA = qa + (tile_m + urow) * Kdim + scol;
  const uint8_t* gB = qb + (tile_n + urow) * Kdim + scol;
  uint8_t* lbase = smem + wave * 1024;         // wave-uniform; + lane*16 by HW

  // unit u (0..1) of matrix mat for K-step tt into ring slot boff
#define STAGE(u, mat, tt, boff)                                            \
  gload_lds16((mat ? gB : gA) + (long long)(u) * 128 * Kdim +              \
                  (long long)(tt) * BK,                                    \
              lbase + (boff) + (mat) * 16384 + (u) * 8192)

  // Fragment read, 64-B rows: lane's 32 logical bytes [kh*32, kh*32+32).
#define FRAG64(dst, tile, row)                                             \
  {                                                                        \
    const int p0_ = (kh * 32) ^ ((((row) >> 1) & 3) << 4);                 \
    const uint8_t* rp_ = (tile) + (row) * 64;                              \
    i32x4 lo_ = ldsr128(rp_ + p0_);                                        \
    i32x4 hi_ = ldsr128(rp_ + (p0_ ^ 16));                                 \
    dst = __builtin_shufflevector(lo_, hi_, 0, 1, 2, 3, 4, 5, 6, 7);       \
  }

  f32x16 acc[4][2] = {};
  const int rowA = wm * 128 + col;   // + m*32
  const int rowB = wn * 64 + col;    // + n*32

  // prologue: stage K-steps 0,1,2 into slots 0,1,2 (12 loads in flight)
#pragma unroll
  for (int tt = 0; tt < 3; ++tt) {
    const uint32_t bo = (uint32_t)tt * SLOT;
    STAGE(0, 0, tt, bo); STAGE(1, 0, tt, bo);
    STAGE(0, 1, tt, bo); STAGE(1, 1, tt, bo);
  }

  for (int t = 0; t < NT; ++t) {
    const uint8_t* Ab = smem + (uint32_t)(t & 3) * SLOT;
    const uint8_t* Bb = Ab + 16384;
    const uint32_t bo = (uint32_t)((t + 3) & 3) * SLOT;

    // head: slot[t]'s 4 loads retired; t+1,t+2 (8 loads) stay in flight
    if (t + 2 < NT)      { VMCNT(8); }
    else if (t + 1 < NT) { VMCNT(4); }
    else                 { VMCNT(0); }
    BARRIER();   // slot[t] visible to all waves; slot[(t+3)&3] free

    // ---- P0: m{0,1} x n{0,1} ----
    i32x8 A0, A1, B0, B1;
    FRAG64(A0, Ab, rowA +  0);
    FRAG64(A1, Ab, rowA + 32);
    FRAG64(B0, Bb, rowB +  0);
    FRAG64(B1, Bb, rowB + 32);
    if (t + 3 < NT) { STAGE(0, 0, t + 3, bo); STAGE(1, 0, t + 3, bo); }
    LGKM(0);
    __builtin_amdgcn_s_setprio(1);
    acc[0][0] = mx(A0, B0, acc[0][0]);  acc[0][1] = mx(A0, B1, acc[0][1]);
    acc[1][0] = mx(A1, B0, acc[1][0]);  acc[1][1] = mx(A1, B1, acc[1][1]);
    __builtin_amdgcn_s_setprio(0);
    BARRIER();   // phase-lock: all waves finish P0 MFMA before P1 ds burst

    // ---- P1: m{2,3} x n{0,1} ----
    i32x8 A2, A3;
    FRAG64(A2, Ab, rowA + 64);
    FRAG64(A3, Ab, rowA + 96);
    if (t + 3 < NT) { STAGE(0, 1, t + 3, bo); STAGE(1, 1, t + 3, bo); }
    LGKM(0);     // all my slot[t] reads complete past this point
    __builtin_amdgcn_s_setprio(1);
    acc[2][0] = mx(A2, B0, acc[2][0]);  acc[2][1] = mx(A2, B1, acc[2][1]);
    acc[3][0] = mx(A3, B0, acc[3][0]);  acc[3][1] = mx(A3, B1, acc[3][1]);
    __builtin_amdgcn_s_setprio(0);
    // no close barrier: next head barrier serves (P1 MFMAs overlap t+1 head)
  }

  // Epilogue.  C/D layout (32x32, dtype-independent): col = lane&31,
  // row = (r&3) + 8*(r>>2) + 4*kh, r in [0,16).  Non-temporal stores keep
  // the streaming output from evicting A/B out of L3 (R11 win).
  const float alpha = iscale[0] * wscale[0];
  const long long col0 = tile_n + wn * 64 + col;
  const float bv0 = bias[col0];
  const float bv1 = bias[col0 + 32];
#pragma unroll
  for (int m = 0; m < 4; ++m) {
#pragma unroll
    for (int r = 0; r < 16; ++r) {
      const long long row =
          tile_m + wm * 128 + m * 32 + (r & 3) + 8 * (r >> 2) + 4 * kh;
      float* op = out + row * (long long)Ndim + col0;
      __builtin_nontemporal_store(acc[m][0][r] * alpha + bv0, op);
      __builtin_nontemporal_store(acc[m][1][r] * alpha + bv1, op + 32);
    }
  }
#undef FRAG64
#undef STAGE
}

extern "C" void kernel_launch(void* const* d_in, const int* in_sizes, int n_in,
                              void* d_out, int out_size, void* d_ws, size_t ws_size,
                              hipStream_t stream) {
  const float* x      = (const float*)d_in[0];  // [4,2048,4096]
  const float* weight = (const float*)d_in[1];  // [14336,4096] (e4m3 lattice)
  const float* wscale = (const float*)d_in[2];  // [1]
  const float* iscale = (const float*)d_in[3];  // [1]
  const float* bias   = (const float*)d_in[4];  // [14336]
  float* out = (float*)d_out;                   // [4,2048,14336]

  uint8_t* qx = (uint8_t*)d_ws;                          // 32 MiB
  uint8_t* qw = qx + (long long)Mdim * Kdim;             // 56 MiB

  const long long nx = (long long)Mdim * Kdim;
  const long long nw = (long long)Ndim * Kdim;

  quant_both_kernel<<<4096, 256, 0, stream>>>(x, weight, qx, qw, iscale, nx, nw);

  dim3 grid(Ndim / BN, Mdim / BM);   // 56 x 32
  gemm_fp8_kernel<<<grid, 512, 0, stream>>>(qx, qw, iscale, wscale, bias, out);
}

// Round 14
// 498.033 us; speedup vs baseline: 1.1689x; 1.1259x over previous
//
#include <hip/hip_runtime.h>
#include <stdint.h>

typedef float    f32x4  __attribute__((ext_vector_type(4)));
typedef float    f32x16 __attribute__((ext_vector_type(16)));
typedef int      i32x4  __attribute__((ext_vector_type(4)));
typedef int      i32x8  __attribute__((ext_vector_type(8)));

constexpr int Mdim = 8192;    // B*S = 4*2048
constexpr int Ndim = 14336;
constexpr int Kdim = 4096;
constexpr int BM = 256, BN = 256, BK = 128;
constexpr int NT = Kdim / BK;        // 32 K-tiles
constexpr uint32_t BUFSZ = 65536;    // one buffer: A(32K) + B(32K)

#define VMCNT(n) asm volatile("s_waitcnt vmcnt(" #n ")" ::: "memory")
#define LGKM(n)  do { asm volatile("s_waitcnt lgkmcnt(" #n ")" ::: "memory"); \
                      __builtin_amdgcn_sched_barrier(0); } while (0)
#define BARRIER() do { asm volatile("" ::: "memory"); \
                       __builtin_amdgcn_s_barrier(); \
                       asm volatile("" ::: "memory"); } while (0)

__device__ __forceinline__ void gload_lds16(const void* g, void* l) {
  __builtin_amdgcn_global_load_lds(
      (const __attribute__((address_space(1))) unsigned int*)g,
      (__attribute__((address_space(3))) unsigned int*)l, 16, 0, 0);
}

__device__ __forceinline__ i32x4 ldsr128(const uint8_t* p) {
  i32x4 r;
  asm volatile("ds_read_b128 %0, %1"
               : "=v"(r)
               : "v"((const __attribute__((address_space(3))) uint8_t*)p));
  return r;
}

// Fragment read: 32 contiguous logical bytes (one 32x32x64 A/B frag per lane)
// at logical byte kb of row `row`; physical byte = logical ^ ((row&7)<<4)
// (T2 swizzle, rule #21 both-sides).
__device__ __forceinline__ i32x8 frag(const uint8_t* tile, int row, int kb) {
  const int p0 = kb ^ ((row & 7) << 4);
  const uint8_t* rp = tile + row * BK;
  i32x4 lo = ldsr128(rp + p0);
  i32x4 hi = ldsr128(rp + (p0 ^ 16));
  return __builtin_shufflevector(lo, hi, 0, 1, 2, 3, 4, 5, 6, 7);
}

__device__ __forceinline__ f32x16 mx(i32x8 a, i32x8 b, f32x16 c) {
  // unit e8m0 scales (0x7f = 2^0): bit-identical to plain fp8 matmul, 2x rate
  return __builtin_amdgcn_mfma_scale_f32_32x32x64_f8f6f4(
      a, b, c, 0, 0, 0, 0x7f7f7f7f, 0, 0x7f7f7f7f);
}

// Merged quantize prepass, 16 elems/thread/iter (4x f32x4 loads in flight
// per iteration -> ~BW-bound; R11's 8-elem version ran at only 3.7 TB/s).
// q = e4m3(clip(v/s, +-448)), RNE via v_cvt_pk_fp8_f32.  x with s=iscale;
// w with s=1 (w values are e4m3 lattice points -> conversion exact).
__global__ void __launch_bounds__(256) quant_both_kernel(
    const float* __restrict__ x, const float* __restrict__ w,
    uint8_t* __restrict__ qx, uint8_t* __restrict__ qw,
    const float* __restrict__ iscale, long long nx, long long nw)
{
  const float sx = iscale[0];
  const long long ncx = nx >> 4, ncw = nw >> 4;   // 16-elem chunks
  const long long total = ncx + ncw;
  const long long idx = (long long)blockIdx.x * blockDim.x + threadIdx.x;
  const long long stride = (long long)gridDim.x * blockDim.x;
  for (long long c = idx; c < total; c += stride) {
    const float* in;
    uint8_t* out8;
    float s;
    long long cc;
    if (c < ncx) { in = x; out8 = qx; s = sx;   cc = c; }
    else         { in = w; out8 = qw; s = 1.0f; cc = c - ncx; }
    const f32x4* src = (const f32x4*)(in + cc * 16);
    f32x4 v0 = src[0], v1 = src[1], v2 = src[2], v3 = src[3];
    float q[16];
#pragma unroll
    for (int j = 0; j < 4; ++j) {
      q[j]      = fminf(fmaxf(v0[j] / s, -448.f), 448.f);
      q[4 + j]  = fminf(fmaxf(v1[j] / s, -448.f), 448.f);
      q[8 + j]  = fminf(fmaxf(v2[j] / s, -448.f), 448.f);
      q[12 + j] = fminf(fmaxf(v3[j] / s, -448.f), 448.f);
    }
    uint32_t r[4];
#pragma unroll
    for (int j = 0; j < 4; ++j) {
      unsigned int pk = 0;
      pk = __builtin_amdgcn_cvt_pk_fp8_f32(q[4 * j],     q[4 * j + 1], pk, false);
      pk = __builtin_amdgcn_cvt_pk_fp8_f32(q[4 * j + 2], q[4 * j + 3], pk, true);
      r[j] = pk;
    }
    uint4 o; o.x = r[0]; o.y = r[1]; o.z = r[2]; o.w = r[3];
    *(uint4*)(out8 + cc * 16) = o;
  }
}

// C = (A @ B^T) * alpha + bias, MX-fp8 unit-scale MFMA.  (R11 verbatim —
// best measured: 423 us GEMM, 57% MfmaUtil.)  256x256 tile, BK=128, 8 waves
// (2M x 4N), per-wave 128x64 = 4x2 frags of 32x32x64.  Counted vmcnt(2)
// staging (T4), counted-lgkmcnt fragment pipeline, setprio (T5), 2 barriers
// per tile with the second moved before the final MFMA cluster.  Epilogue
// non-temporal stores keep the 470 MB output stream from evicting the 88 MB
// A+B working set out of L3 (FETCH 500->390 MB, R11 win).
__global__ void __launch_bounds__(512, 2) gemm_fp8_kernel(
    const uint8_t* __restrict__ qa, const uint8_t* __restrict__ qb,
    const float* __restrict__ iscale, const float* __restrict__ wscale,
    const float* __restrict__ bias, float* __restrict__ out)
{
  __shared__ uint8_t smem[2 * BUFSZ];   // 128 KiB

  const int tid  = threadIdx.x;
  const int wave = tid >> 6;
  const int lane = tid & 63;
  const int wm   = wave >> 2;       // 0..1
  const int wn   = wave & 3;        // 0..3
  const int col  = lane & 31;
  const int kh   = lane >> 5;
  const long long tile_m = (long long)blockIdx.y * BM;
  const long long tile_n = (long long)blockIdx.x * BN;

  // Staging: unit = 64 rows x 128 B = 8 KiB = 512 thr x 16 B (1 gload/thr).
  // Thread -> row tid>>3, physical block tid&7; source block = pb ^ (row&7).
  const int urow = tid >> 3;                   // 0..63
  const int pbs  = tid & 7;
  const int scol = (pbs ^ (urow & 7)) << 4;
  const uint8_t* gA = qa + (tile_m + urow) * Kdim + scol;
  const uint8_t* gB = qb + (tile_n + urow) * Kdim + scol;
  uint8_t* lbase = smem + wave * 1024;         // wave-uniform; + lane*16 by HW

#define STAGE(u, mat, k0, boff)                                           \
  gload_lds16((mat ? gB : gA) + (long long)(u) * 64 * Kdim + (k0),        \
              lbase + (boff) + (mat) * 32768 + (u) * 8192)

  f32x16 acc[4][2] = {};

  const int rowA = wm * 128 + col;   // + m*32
  const int rowB = wn * 64 + col;    // + n*32
  const int kb0 = kh * 32;           // ks=0 logical byte
  const int kb1 = 64 + kh * 32;      // ks=1

  // prologue: stage tile 0 into buffer 0 (8 loads in flight)
#pragma unroll
  for (int u = 0; u < 4; ++u) STAGE(u, 0, 0, 0);
#pragma unroll
  for (int u = 0; u < 4; ++u) STAGE(u, 1, 0, 0);

  uint32_t cur = 0;
  for (int t = 0; t < NT - 1; ++t) {
    const long long kn = (long long)(t + 1) * BK;
    const uint32_t nxt = cur ^ BUFSZ;
    const uint8_t* Ab = smem + cur;
    const uint8_t* Bb = smem + cur + 32768;

    STAGE(0, 0, kn, nxt); STAGE(1, 0, kn, nxt);
    VMCNT(2);             // tile t's 8 loads retired; t+1's 2 stay in flight
    BARRIER();            // buf[cur] tile-t data visible to all waves

    // P0 issue (8 ds_reads): ks0 m{0,1} + B pair
    i32x8 A0 = frag(Ab, rowA +  0, kb0);
    i32x8 A1 = frag(Ab, rowA + 32, kb0);
    i32x8 B0 = frag(Bb, rowB +  0, kb0);
    i32x8 B1 = frag(Bb, rowB + 32, kb0);
    STAGE(2, 0, kn, nxt); STAGE(3, 0, kn, nxt);
    // P1 issue (4): ks0 m{2,3}
    i32x8 A2 = frag(Ab, rowA + 64, kb0);
    i32x8 A3 = frag(Ab, rowA + 96, kb0);
    LGKM(4);              // P0 frags ready; P1's 4 reads still in flight
    __builtin_amdgcn_s_setprio(1);
    acc[0][0] = mx(A0, B0, acc[0][0]);  acc[0][1] = mx(A0, B1, acc[0][1]);
    acc[1][0] = mx(A1, B0, acc[1][0]);  acc[1][1] = mx(A1, B1, acc[1][1]);
    __builtin_amdgcn_s_setprio(0);

    STAGE(0, 1, kn, nxt); STAGE(1, 1, kn, nxt);
    // P2 issue (8): ks1 m{0,1} + B pair (primed set)
    i32x8 A0p = frag(Ab, rowA +  0, kb1);
    i32x8 A1p = frag(Ab, rowA + 32, kb1);
    i32x8 B0p = frag(Bb, rowB +  0, kb1);
    i32x8 B1p = frag(Bb, rowB + 32, kb1);
    LGKM(8);              // P1 frags ready; P2's 8 in flight
    __builtin_amdgcn_s_setprio(1);
    acc[2][0] = mx(A2, B0, acc[2][0]);  acc[2][1] = mx(A2, B1, acc[2][1]);
    acc[3][0] = mx(A3, B0, acc[3][0]);  acc[3][1] = mx(A3, B1, acc[3][1]);
    __builtin_amdgcn_s_setprio(0);

    STAGE(2, 1, kn, nxt); STAGE(3, 1, kn, nxt);
    // P3 issue (4): ks1 m{2,3}
    i32x8 A2p = frag(Ab, rowA + 64, kb1);
    i32x8 A3p = frag(Ab, rowA + 96, kb1);
    LGKM(4);              // P2 frags ready; P3's 4 in flight
    __builtin_amdgcn_s_setprio(1);
    acc[0][0] = mx(A0p, B0p, acc[0][0]);  acc[0][1] = mx(A0p, B1p, acc[0][1]);
    acc[1][0] = mx(A1p, B0p, acc[1][0]);  acc[1][1] = mx(A1p, B1p, acc[1][1]);
    __builtin_amdgcn_s_setprio(0);
    LGKM(0);              // P3 frags ready; ALL my reads of buf[cur] done
    BARRIER();            // every wave past lgkm(0) -> all reads of buf[cur]
                          // complete; next tile may overwrite it.
    __builtin_amdgcn_s_setprio(1);
    acc[2][0] = mx(A2p, B0p, acc[2][0]);  acc[2][1] = mx(A2p, B1p, acc[2][1]);
    acc[3][0] = mx(A3p, B0p, acc[3][0]);  acc[3][1] = mx(A3p, B1p, acc[3][1]);
    __builtin_amdgcn_s_setprio(0);

    cur = nxt;
  }

  // ---- tail tile NT-1 (no prefetch), same lgkm pipeline ----
  {
    const uint8_t* Ab = smem + cur;
    const uint8_t* Bb = smem + cur + 32768;
    VMCNT(0);
    BARRIER();
    i32x8 A0 = frag(Ab, rowA +  0, kb0);
    i32x8 A1 = frag(Ab, rowA + 32, kb0);
    i32x8 B0 = frag(Bb, rowB +  0, kb0);
    i32x8 B1 = frag(Bb, rowB + 32, kb0);
    i32x8 A2 = frag(Ab, rowA + 64, kb0);
    i32x8 A3 = frag(Ab, rowA + 96, kb0);
    LGKM(4);
    acc[0][0] = mx(A0, B0, acc[0][0]);  acc[0][1] = mx(A0, B1, acc[0][1]);
    acc[1][0] = mx(A1, B0, acc[1][0]);  acc[1][1] = mx(A1, B1, acc[1][1]);
    i32x8 A0p = frag(Ab, rowA +  0, kb1);
    i32x8 A1p = frag(Ab, rowA + 32, kb1);
    i32x8 B0p = frag(Bb, rowB +  0, kb1);
    i32x8 B1p = frag(Bb, rowB + 32, kb1);
    LGKM(8);
    acc[2][0] = mx(A2, B0, acc[2][0]);  acc[2][1] = mx(A2, B1, acc[2][1]);
    acc[3][0] = mx(A3, B0, acc[3][0]);  acc[3][1] = mx(A3, B1, acc[3][1]);
    i32x8 A2p = frag(Ab, rowA + 64, kb1);
    i32x8 A3p = frag(Ab, rowA + 96, kb1);
    LGKM(4);
    acc[0][0] = mx(A0p, B0p, acc[0][0]);  acc[0][1] = mx(A0p, B1p, acc[0][1]);
    acc[1][0] = mx(A1p, B0p, acc[1][0]);  acc[1][1] = mx(A1p, B1p, acc[1][1]);
    LGKM(0);
    acc[2][0] = mx(A2p, B0p, acc[2][0]);  acc[2][1] = mx(A2p, B1p, acc[2][1]);
    acc[3][0] = mx(A3p, B0p, acc[3][0]);  acc[3][1] = mx(A3p, B1p, acc[3][1]);
  }

  // Epilogue.  C/D layout (32x32, dtype-independent): col = lane&31,
  // row = (r&3) + 8*(r>>2) + 4*kh, r in [0,16).  Non-temporal stores.
  const float alpha = iscale[0] * wscale[0];
  const long long col0 = tile_n + wn * 64 + col;
  const float bv0 = bias[col0];
  const float bv1 = bias[col0 + 32];
#pragma unroll
  for (int m = 0; m < 4; ++m) {
#pragma unroll
    for (int r = 0; r < 16; ++r) {
      const long long row =
          tile_m + wm * 128 + m * 32 + (r & 3) + 8 * (r >> 2) + 4 * kh;
      float* op = out + row * (long long)Ndim + col0;
      __builtin_nontemporal_store(acc[m][0][r] * alpha + bv0, op);
      __builtin_nontemporal_store(acc[m][1][r] * alpha + bv1, op + 32);
    }
  }
#undef STAGE
}

extern "C" void kernel_launch(void* const* d_in, const int* in_sizes, int n_in,
                              void* d_out, int out_size, void* d_ws, size_t ws_size,
                              hipStream_t stream) {
  const float* x      = (const float*)d_in[0];  // [4,2048,4096]
  const float* weight = (const float*)d_in[1];  // [14336,4096] (e4m3 lattice)
  const float* wscale = (const float*)d_in[2];  // [1]
  const float* iscale = (const float*)d_in[3];  // [1]
  const float* bias   = (const float*)d_in[4];  // [14336]
  float* out = (float*)d_out;                   // [4,2048,14336]

  uint8_t* qx = (uint8_t*)d_ws;                          // 32 MiB
  uint8_t* qw = qx + (long long)Mdim * Kdim;             // 56 MiB

  const long long nx = (long long)Mdim * Kdim;
  const long long nw = (long long)Ndim * Kdim;

  quant_both_kernel<<<4096, 256, 0, stream>>>(x, weight, qx, qw, iscale, nx, nw);

  dim3 grid(Ndim / BN, Mdim / BM);   // 56 x 32
  gemm_fp8_kernel<<<grid, 512, 0, stream>>>(qx, qw, iscale, wscale, bias, out);
}